// Round 9
// baseline (125.763 us; speedup 1.0000x reference)
//
#include <hip/hip_runtime.h>

// BarrierNet fused MLP + CBF-QP filter — f16 MFMA, weights in LDS, 2-chain
// ILP, 3 waves/EU.
//
// R8 lessons: (a) layer-1 x-tile is 128 cols wide -> XSTR must be >=128
// (R8's 72 corrupted it, absmax 7.0); (b) NT=4 straight-line blew the 32KB
// I-cache (VALUBusy fell); (c) weights-in-registers (104 regs/wave) pin
// combined reg use ~190-230 -> hard 2 waves/SIMD ceiling.
//
// R9: weights+biases live in LDS (staged once per block from prepacked d_ws,
// one __syncthreads after staging). B-fragments are ds_read_b128 at
// base+imm per use. Per-wave live set ~110 regs -> __launch_bounds__(256,3)
// = 3 waves/EU. NT=2 chains share ONE x-slot per wave: DS ops execute in
// program order per wave, so c0-writes < c0-reads < c1-writes to the same
// addresses is safe, while MFMA/VALU of the two chains still interleave.
// LDS/block = 29952 (weights) + 4*4352 (x-slots) + 2048 (ep) = 49408 B
// -> 3 blocks/CU.
//
// Layouts (HW-verified, learn_hip m89/m91/m120):
//   A-frag: lane holds A[m=lane&15][k=(lane>>4)*8 + j], j=0..7
//   B-frag: lane holds B[k=(lane>>4)*8+j][n=lane&15]  (= W[n][k], W:[out,in])
//   C/D   : lane holds D[row=(lane>>4)*4+reg][col=lane&15]

typedef _Float16 half8 __attribute__((ext_vector_type(8)));
typedef float floatx4 __attribute__((ext_vector_type(4)));

#define TPB   256
#define NW    4         // waves per block
#define XSTR  136       // x-slot row stride in halfs (>=128 cols + pad, 272 B)

// d_ws layout (bytes); WS_FRAG..WS_END is copied verbatim into LDS.
#define WS_FRAG 0        // 26*64 half8  = 26624 B  (fragID-major, lane-minor)
#define WS_B1   26624    // 8*64 float   =  2048 B   b1f[nt][lane]
#define WS_B2   28672    // 4*64 float   =  1024 B   b2f[nt2][lane]
#define WS_B3   29696    // 64 float     =   256 B   b3v[lane]
#define WS_END  29952

// LDS layout (bytes)
#define L_XS    29952                  // NW x-slots, 16*XSTR halfs each
#define L_EP    (29952 + NW*16*XSTR*2) // NW*2 ep slots, 16*4 floats each
#define L_TOTAL (L_EP + NW*2*16*4*4)   // = 49408

__device__ __forceinline__ float fast_sigmoid(float z) {
    return __builtin_amdgcn_rcpf(1.0f + __expf(-z));
}

// ---------------- prep: fp32 weights -> f16 fragments in ws ----------------
__global__ __launch_bounds__(256) void prep_kernel(
    const float* __restrict__ W1,  const float* __restrict__ b1,
    const float* __restrict__ W21, const float* __restrict__ b21,
    const float* __restrict__ W22, const float* __restrict__ b22,
    const float* __restrict__ W31, const float* __restrict__ b31,
    const float* __restrict__ W32, const float* __restrict__ b32,
    unsigned char* __restrict__ ws)
{
    const int tid  = blockIdx.x * 256 + threadIdx.x;
    const int lane = tid & 63;
    const int m    = lane & 15;
    const int q    = lane >> 4;

    if (tid < 26 * 64) {
        const int f = tid >> 6;
        float v[8];
        if (f < 8) {                         // layer 1: W1 [128][10], K pad->32
            const float* wr = W1 + (f * 16 + m) * 10;
            #pragma unroll
            for (int j = 0; j < 8; ++j) {
                const int k = q * 8 + j;
                v[j] = (k < 10) ? wr[k] : 0.0f;
            }
        } else if (f < 24) {                 // layer 2: cat[W21;W22] [64][128]
            const int f2 = f - 8, nt2 = f2 >> 2, kt = f2 & 3;
            const int n2 = nt2 * 16 + m;
            const float* wr = (n2 < 32) ? (W21 + n2 * 128)
                                        : (W22 + (n2 - 32) * 128);
            #pragma unroll
            for (int j = 0; j < 8; ++j) v[j] = wr[kt * 32 + q * 8 + j];
        } else if (f == 24) {                // layer 3 kt=0: W31 rows, n=0,1
            #pragma unroll
            for (int j = 0; j < 8; ++j)
                v[j] = (m < 2) ? W31[m * 32 + q * 8 + j] : 0.0f;
        } else {                             // layer 3 kt=1: W32, n=2
            #pragma unroll
            for (int j = 0; j < 8; ++j)
                v[j] = (m == 2) ? W32[q * 8 + j] : 0.0f;
        }
        half8 h;
        #pragma unroll
        for (int j = 0; j < 8; ++j) h[j] = (_Float16)v[j];
        ((half8*)(ws + WS_FRAG))[tid] = h;
    }
    if (tid < 512)
        ((float*)(ws + WS_B1))[tid] = b1[(tid >> 6) * 16 + (tid & 15)];
    if (tid < 256) {
        const int n2 = (tid >> 6) * 16 + (tid & 15);
        ((float*)(ws + WS_B2))[tid] = (n2 < 32) ? b21[n2] : b22[n2 - 32];
    }
    if (tid < 64) {
        const int mm = tid & 15;
        ((float*)(ws + WS_B3))[tid] =
            (mm == 0) ? b31[0] : (mm == 1) ? b31[1] : (mm == 2) ? b32[0] : 0.0f;
    }
}

// ------------------------------- main -------------------------------------
__global__ __launch_bounds__(TPB, 3) void barriernet_kernel(
    const float* __restrict__ obs,
    const unsigned char* __restrict__ ws,
    float* __restrict__ out, int B)
{
    __shared__ __align__(16) unsigned char lds[L_TOTAL];

    const int tid  = threadIdx.x;
    const int wave = tid >> 6;
    const int lane = tid & 63;
    const int m    = lane & 15;
    const int q    = lane >> 4;

    // ---- stage weights+biases ws -> LDS (29952 B = 1872 float4) ----
    {
        const float4* src = (const float4*)ws;
        float4* dst = (float4*)lds;
        for (int i = tid; i < WS_END / 16; i += TPB) dst[i] = src[i];
    }
    __syncthreads();   // once; hot path below is barrier-free

    const _Float16* wl  = (const _Float16*)lds;             // fragments
    const float*    lb1 = (const float*)(lds + WS_B1);
    const float*    lb2 = (const float*)(lds + WS_B2);
    const float*    lb3 = (const float*)(lds + WS_B3);

    // biases -> registers (13 ds_read_b32, wave-uniform-per-lane pattern)
    float b1f[8], b2f[4];
    #pragma unroll
    for (int nt = 0; nt < 8; ++nt) b1f[nt] = lb1[nt * 64 + lane];
    #pragma unroll
    for (int nt2 = 0; nt2 < 4; ++nt2) b2f[nt2] = lb2[nt2 * 64 + lane];
    const float b3v = lb3[lane];

    // B-fragment read: fragID f at byte offset f*1024 + lane*16 (imm + base)
    const _Float16* wbase = wl + lane * 8;
    #define WFRAG(f) (*(const half8*)(wbase + (f) * 512))

    // x-slot (shared by both chains of this wave; DS program order protects)
    _Float16* xsl = (_Float16*)(lds + L_XS) + wave * 16 * XSTR;
    _Float16* xq  = xsl + q * 4 * XSTR + m;                 // write base
    const half8* xr = (const half8*)(xsl + m * XSTR + q * 8); // read base
    float* epw = (float*)(lds + L_EP) + wave * 2 * 64;      // 2 chains x 64

    const int tiles = (B + 15) >> 4;
    const int tbase = (blockIdx.x * NW + wave) * 2;

    // --- obs rows + A1 fragments for both chains (loads back-to-back) ---
    const float* orow[2];
    half8 a1[2];
    int lrow0[2];
    #pragma unroll
    for (int p = 0; p < 2; ++p) {
        int tile = tbase + p;
        if (tile >= tiles) tile = tiles - 1;            // dup work, benign
        int lr = (tile << 4) + m;
        if (lr >= B) lr = B - 1;
        lrow0[p] = lr;
        orow[p] = obs + (size_t)lr * 10;

        float g0=0,g1=0,g2=0,g3=0,g4=0,g5=0,g6=0,g7=0;
        if (q == 0) {
            float2 p0 = *(const float2*)(orow[p] + 0);
            float2 p1 = *(const float2*)(orow[p] + 2);
            float2 p2 = *(const float2*)(orow[p] + 4);
            float2 p3 = *(const float2*)(orow[p] + 6);
            g0=p0.x; g1=p0.y; g2=p1.x; g3=p1.y;
            g4=p2.x; g5=p2.y; g6=p3.x; g7=p3.y;
        } else if (q == 1) {
            float2 pp = *(const float2*)(orow[p] + 8);
            g0=pp.x; g1=pp.y;
        }
        a1[p][0]=(_Float16)g0; a1[p][1]=(_Float16)g1;
        a1[p][2]=(_Float16)g2; a1[p][3]=(_Float16)g3;
        a1[p][4]=(_Float16)g4; a1[p][5]=(_Float16)g5;
        a1[p][6]=(_Float16)g6; a1[p][7]=(_Float16)g7;
    }

    half8 a2[2][4];

    // ---- phase: c0 layer 1 -> x-slot; c0 a2 reads ----
    #pragma unroll
    for (int nt = 0; nt < 8; ++nt) {
        floatx4 z = {b1f[nt], b1f[nt], b1f[nt], b1f[nt]};
        z = __builtin_amdgcn_mfma_f32_16x16x32_f16(a1[0], WFRAG(nt), z, 0, 0, 0);
        #pragma unroll
        for (int r = 0; r < 4; ++r) {
            float zz = z[r];
            xq[r * XSTR + nt * 16] = (_Float16)(zz * fast_sigmoid(zz));
        }
    }
    #pragma unroll
    for (int kt = 0; kt < 4; ++kt) a2[0][kt] = xr[kt * 4];

    // ---- phase: c1 layer 1 (same slot, DS-ordered after c0 reads) ----
    #pragma unroll
    for (int nt = 0; nt < 8; ++nt) {
        floatx4 z = {b1f[nt], b1f[nt], b1f[nt], b1f[nt]};
        z = __builtin_amdgcn_mfma_f32_16x16x32_f16(a1[1], WFRAG(nt), z, 0, 0, 0);
        #pragma unroll
        for (int r = 0; r < 4; ++r) {
            float zz = z[r];
            xq[r * XSTR + nt * 16] = (_Float16)(zz * fast_sigmoid(zz));
        }
    }
    #pragma unroll
    for (int kt = 0; kt < 4; ++kt) a2[1][kt] = xr[kt * 4];

    // ---- phase: c0 layer 2 -> x-slot; c0 a3 reads ----
    half8 a3[2][2];
    #pragma unroll
    for (int nt2 = 0; nt2 < 4; ++nt2) {
        floatx4 z = {b2f[nt2], b2f[nt2], b2f[nt2], b2f[nt2]};
        #pragma unroll
        for (int kt = 0; kt < 4; ++kt)
            z = __builtin_amdgcn_mfma_f32_16x16x32_f16(a2[0][kt], WFRAG(8 + nt2 * 4 + kt), z, 0, 0, 0);
        #pragma unroll
        for (int r = 0; r < 4; ++r) {
            float zz = z[r];
            xq[r * XSTR + nt2 * 16] = (_Float16)(zz * fast_sigmoid(zz));
        }
    }
    a3[0][0] = xr[0];
    a3[0][1] = xr[4];

    // ---- phase: c1 layer 2; c1 a3 reads ----
    #pragma unroll
    for (int nt2 = 0; nt2 < 4; ++nt2) {
        floatx4 z = {b2f[nt2], b2f[nt2], b2f[nt2], b2f[nt2]};
        #pragma unroll
        for (int kt = 0; kt < 4; ++kt)
            z = __builtin_amdgcn_mfma_f32_16x16x32_f16(a2[1][kt], WFRAG(8 + nt2 * 4 + kt), z, 0, 0, 0);
        #pragma unroll
        for (int r = 0; r < 4; ++r) {
            float zz = z[r];
            xq[r * XSTR + nt2 * 16] = (_Float16)(zz * fast_sigmoid(zz));
        }
    }
    a3[1][0] = xr[0];
    a3[1][1] = xr[4];

    // ---- heads + ep writes ----
    #pragma unroll
    for (int p = 0; p < 2; ++p) {
        floatx4 d = {b3v, b3v, b3v, b3v};
        d = __builtin_amdgcn_mfma_f32_16x16x32_f16(a3[p][0], WFRAG(24), d, 0, 0, 0);
        d = __builtin_amdgcn_mfma_f32_16x16x32_f16(a3[p][1], WFRAG(25), d, 0, 0, 0);
        if (m < 3) {
            #pragma unroll
            for (int r = 0; r < 4; ++r)
                epw[p * 64 + (q * 4 + r) * 4 + m] = d[r];
        }
    }

    // ---- fp32 CBF-QP epilogue: quad-0 lanes, one row per lane per chain ----
    #pragma unroll
    for (int p = 0; p < 2; ++p) {
        if (q == 0) {
            float4 e = ((const float4*)(epw + p * 64))[m];
            const float u0 = e.x, u1 = e.y, z32 = e.z;
            const float alpha = 4.0f * fast_sigmoid(z32);

            const float2 rxy = *(const float2*)(orow[p] + 6);
            const float2 vxy = *(const float2*)(orow[p] + 8);
            const float rx = rxy.x, ry = rxy.y, vx = vxy.x, vy = vxy.y;

            const float barrier = rx * rx + ry * ry - 0.64f;   // R_SAFE^2
            const float lf = -2.0f * (rx * vx + ry * vy);
            const float gx = -2.0f * rx, gy = -2.0f * ry;
            const float h  = lf + alpha * barrier;
            const float gg = gx * gx + gy * gy;
            const float viol = gx * u0 + gy * u1 - h;
            float lam = 0.0f;
            if (gg > 0.0f) lam = fmaxf(viol, 0.0f) / fmaxf(gg, 1e-12f);

            float2 r;
            r.x = fmaf(-lam, gx, u0);
            r.y = fmaf(-lam, gy, u1);
            *(float2*)(out + (size_t)lrow0[p] * 2) = r;
        }
    }
    #undef WFRAG
}

extern "C" void kernel_launch(void* const* d_in, const int* in_sizes, int n_in,
                              void* d_out, int out_size, void* d_ws, size_t ws_size,
                              hipStream_t stream) {
    const float* obs = (const float*)d_in[0];
    const float* W1  = (const float*)d_in[1];
    const float* b1  = (const float*)d_in[2];
    const float* W21 = (const float*)d_in[3];
    const float* b21 = (const float*)d_in[4];
    const float* W22 = (const float*)d_in[5];
    const float* b22 = (const float*)d_in[6];
    const float* W31 = (const float*)d_in[7];
    const float* b31 = (const float*)d_in[8];
    const float* W32 = (const float*)d_in[9];
    const float* b32 = (const float*)d_in[10];

    unsigned char* ws = (unsigned char*)d_ws;

    // prep: 26*64 fragment threads -> 7 blocks of 256
    prep_kernel<<<7, 256, 0, stream>>>(W1, b1, W21, b21, W22, b22,
                                       W31, b31, W32, b32, ws);

    const int B = in_sizes[0] / 10;                  // obs is [B,10]
    const int tiles = (B + 15) / 16;                 // 32768
    const int pairs = (tiles + 1) / 2;               // 16384
    const int grid  = (pairs + NW - 1) / NW;         // 4096

    barriernet_kernel<<<grid, TPB, 0, stream>>>(obs, ws, (float*)d_out, B);
}

// Round 10
// 124.017 us; speedup vs baseline: 1.0141x; 1.0141x over previous
//
#include <hip/hip_runtime.h>

// BarrierNet fused MLP + CBF-QP filter — output-transposed f16 MFMA, zero-LDS
// hot path.
//
// Trick 1: compute every layer transposed, D = W·Xᵀ. A-layout and B-layout
// share the lane mapping (non-k index = lane&15, k = (lane>>4)*8+j), so this
// is just operand-order swap: mfma(Wfrag, Xfrag) -> D[out][row].
// Trick 2: the next layer's k-index = this layer's out-channel; since WE
// prepack the weights, renumber layer-(N+1) weights with
//   H(kt,q,j) = (2kt+(j>>2))*16 + q*4 + (j&3)
// so the next B-fragment is built IN-LANE from this layer's C-layout accs:
//   b2frag[kt][j] = silu(acc[2kt+(j>>2)][j&3])     (same lane, no movement!)
// -> the C->A transpose (R4-R9: 48 ds_write_b16 + ds_read_b128 + 2 lgkm
// serialization points per tile) disappears. No LDS, no barriers at all.
// Trick 3: L3 transposed output lands u0,u1,z32 for row m in lane (q=0,m)
// registers -> epilogue straight from registers, coalesced float2 store.
// Trick 4: L1 bias rides the k=10 pad slot (obs k=10 := 1.0, W1 k=10 := b1).
//
// 2 interleaved chains per wave (R7's proven ILP), weights in registers
// (104 regs, shared by both chains; R9 showed LDS-resident weights regress).
// __launch_bounds__(256,2): R4/R5 measured (256,3+) -> scratch spills.
//
// Layouts (HW-verified, learn_hip m89/m91/m120):
//   A-frag: lane holds A[m=lane&15][k=(lane>>4)*8 + j], j=0..7
//   B-frag: lane holds B[k=(lane>>4)*8+j][n=lane&15]
//   C/D   : lane holds D[row=(lane>>4)*4+reg][col=lane&15]

typedef _Float16 half8 __attribute__((ext_vector_type(8)));
typedef float floatx4 __attribute__((ext_vector_type(4)));

#define TPB 256
#define NW  4          // waves per block

// d_ws layout (bytes). Fragments: half8[fragID][lane]; fragID 0..7 = W1
// n-tiles (k=10 slot carries b1), 8..23 = W2 (nt2*4+kt, H-permuted k),
// 24..25 = W3 heads (H-permuted k). Then bias table for L2 C-init.
#define WS_FRAG 0        // 26*64 half8 = 26624 B
#define WS_B2Q  26624    // 16 float4  =   256 B   [nt2][q] -> {bias r=0..3}

__device__ __forceinline__ float fast_sigmoid(float z) {
    return __builtin_amdgcn_rcpf(1.0f + __expf(-z));
}

// ---------------- prep: fp32 weights -> f16 fragments in ws ----------------
__global__ __launch_bounds__(256) void prep_kernel(
    const float* __restrict__ W1,  const float* __restrict__ b1,
    const float* __restrict__ W21, const float* __restrict__ b21,
    const float* __restrict__ W22, const float* __restrict__ b22,
    const float* __restrict__ W31, const float* __restrict__ b31,
    const float* __restrict__ W32, const float* __restrict__ b32,
    unsigned char* __restrict__ ws)
{
    const int tid  = blockIdx.x * 256 + threadIdx.x;
    const int lane = tid & 63;
    const int m    = lane & 15;
    const int q    = lane >> 4;

    if (tid < 26 * 64) {
        const int f = tid >> 6;
        float v[8];
        if (f < 8) {
            // Ŵ1 A-frag, n-tile f: A[m][k=q*8+j]; k<10 -> W1, k==10 -> b1.
            const float* wr = W1 + (f * 16 + m) * 10;
            #pragma unroll
            for (int j = 0; j < 8; ++j) {
                const int k = q * 8 + j;
                v[j] = (k < 10) ? wr[k] : (k == 10 ? b1[f * 16 + m] : 0.0f);
            }
        } else if (f < 24) {
            // Ŵ2 A-frag (nt2,kt), H-permuted k-order to match in-lane pack.
            const int f2 = f - 8, nt2 = f2 >> 2, kt = f2 & 3;
            const int n2 = nt2 * 16 + m;
            const float* wr = (n2 < 32) ? (W21 + n2 * 128)
                                        : (W22 + (n2 - 32) * 128);
            #pragma unroll
            for (int j = 0; j < 8; ++j) {
                const int H = (2 * kt + (j >> 2)) * 16 + q * 4 + (j & 3);
                v[j] = wr[H];
            }
        } else {
            // Ŵ3 A-frag kt3: rows = heads (u0,u1 from W31 over n2<32; z32
            // from W32 over n2>=32), H3-permuted k-order.
            const int kt3 = f - 24;
            #pragma unroll
            for (int j = 0; j < 8; ++j) {
                const int H3 = (2 * kt3 + (j >> 2)) * 16 + q * 4 + (j & 3);
                float x = 0.0f;
                if (m == 0)      x = (H3 < 32)  ? W31[H3]       : 0.0f;
                else if (m == 1) x = (H3 < 32)  ? W31[32 + H3]  : 0.0f;
                else if (m == 2) x = (H3 >= 32) ? W32[H3 - 32]  : 0.0f;
                v[j] = x;
            }
        }
        half8 h;
        #pragma unroll
        for (int j = 0; j < 8; ++j) h[j] = (_Float16)v[j];
        ((half8*)(ws + WS_FRAG))[tid] = h;
    }
    if (tid < 16) {
        // L2 bias C-init table: [nt2][q] -> bias for out = nt2*16+q*4+r.
        const int nt2 = tid >> 2, qq = tid & 3;
        float4 v;
        float* vp = (float*)&v;
        #pragma unroll
        for (int r = 0; r < 4; ++r) {
            const int n2 = nt2 * 16 + qq * 4 + r;
            vp[r] = (n2 < 32) ? b21[n2] : b22[n2 - 32];
        }
        ((float4*)(ws + WS_B2Q))[tid] = v;
    }
}

// ------------------------------- main -------------------------------------
__global__ __launch_bounds__(TPB, 2) void barriernet_kernel(
    const float* __restrict__ obs,
    const unsigned char* __restrict__ ws,
    const float* __restrict__ b31, const float* __restrict__ b32,
    float* __restrict__ out, int B)
{
    const int tid  = threadIdx.x;
    const int wave = tid >> 6;
    const int lane = tid & 63;
    const int m    = lane & 15;
    const int q    = lane >> 4;

    // ---- weight fragments: 26 coalesced b128 loads + 4 float4 bias loads ----
    const half8* wf = (const half8*)(ws + WS_FRAG);
    half8 w1f[8], w2f[16], w3f0, w3f1;
    #pragma unroll
    for (int nt = 0; nt < 8; ++nt)  w1f[nt] = wf[nt * 64 + lane];
    #pragma unroll
    for (int f2 = 0; f2 < 16; ++f2) w2f[f2] = wf[(8 + f2) * 64 + lane];
    w3f0 = wf[24 * 64 + lane];
    w3f1 = wf[25 * 64 + lane];

    const float4* bt = (const float4*)(ws + WS_B2Q);
    float4 b2q[4];
    #pragma unroll
    for (int nt2 = 0; nt2 < 4; ++nt2) b2q[nt2] = bt[nt2 * 4 + q];

    const float bu0 = b31[0], bu1 = b31[1], bz3 = b32[0];  // uniform scalars

    const int tiles = (B + 15) >> 4;
    const int tbase = (blockIdx.x * NW + wave) * 2;

    // --- obs B-fragments for both chains (loads issue back-to-back) ---
    // B-frag: lane (q,m) holds obs[row=m][k=q*8+j]; k=10 slot := 1.0 (bias).
    const float* orow[2];
    half8 xf[2];
    int lrow0[2];
    #pragma unroll
    for (int p = 0; p < 2; ++p) {
        int tile = tbase + p;
        if (tile >= tiles) tile = tiles - 1;            // dup work, benign
        int lr = (tile << 4) + m;
        if (lr >= B) lr = B - 1;
        lrow0[p] = lr;
        orow[p] = obs + (size_t)lr * 10;

        float g0=0,g1=0,g2=0,g3=0,g4=0,g5=0,g6=0,g7=0;
        if (q == 0) {
            float2 p0 = *(const float2*)(orow[p] + 0);
            float2 p1 = *(const float2*)(orow[p] + 2);
            float2 p2 = *(const float2*)(orow[p] + 4);
            float2 p3 = *(const float2*)(orow[p] + 6);
            g0=p0.x; g1=p0.y; g2=p1.x; g3=p1.y;
            g4=p2.x; g5=p2.y; g6=p3.x; g7=p3.y;
        } else if (q == 1) {
            float2 pp = *(const float2*)(orow[p] + 8);
            g0=pp.x; g1=pp.y;
            g2=1.0f;                                   // k=10: bias lane
        }
        xf[p][0]=(_Float16)g0; xf[p][1]=(_Float16)g1;
        xf[p][2]=(_Float16)g2; xf[p][3]=(_Float16)g3;
        xf[p][4]=(_Float16)g4; xf[p][5]=(_Float16)g5;
        xf[p][6]=(_Float16)g6; xf[p][7]=(_Float16)g7;
    }

    // --- layer 1: D[out][row], 8 n-tiles per chain, interleaved ---
    floatx4 acc[2][8];
    #pragma unroll
    for (int nt = 0; nt < 8; ++nt) {
        #pragma unroll
        for (int p = 0; p < 2; ++p) {
            floatx4 z = {0.0f, 0.0f, 0.0f, 0.0f};
            acc[p][nt] = __builtin_amdgcn_mfma_f32_16x16x32_f16(
                             w1f[nt], xf[p], z, 0, 0, 0);
        }
    }

    // --- silu + in-lane pack to L2 B-fragments (H-order, no cross-lane) ---
    half8 b2f[2][4];
    #pragma unroll
    for (int p = 0; p < 2; ++p) {
        #pragma unroll
        for (int kt = 0; kt < 4; ++kt) {
            half8 bf;
            #pragma unroll
            for (int jj = 0; jj < 4; ++jj) {
                float z0 = acc[p][2 * kt][jj];
                float z1 = acc[p][2 * kt + 1][jj];
                bf[jj]     = (_Float16)(z0 * fast_sigmoid(z0));
                bf[jj + 4] = (_Float16)(z1 * fast_sigmoid(z1));
            }
            b2f[p][kt] = bf;
        }
    }

    // --- layer 2: 4 n-tiles x 4 k-steps per chain, bias C-init ---
    floatx4 acc2[2][4];
    #pragma unroll
    for (int nt2 = 0; nt2 < 4; ++nt2) {
        #pragma unroll
        for (int p = 0; p < 2; ++p) {
            floatx4 z = {b2q[nt2].x, b2q[nt2].y, b2q[nt2].z, b2q[nt2].w};
            #pragma unroll
            for (int kt = 0; kt < 4; ++kt)
                z = __builtin_amdgcn_mfma_f32_16x16x32_f16(
                        w2f[nt2 * 4 + kt], b2f[p][kt], z, 0, 0, 0);
            acc2[p][nt2] = z;
        }
    }

    // --- silu + in-lane pack to L3 B-fragments ---
    half8 b3f[2][2];
    #pragma unroll
    for (int p = 0; p < 2; ++p) {
        #pragma unroll
        for (int kt3 = 0; kt3 < 2; ++kt3) {
            half8 bf;
            #pragma unroll
            for (int jj = 0; jj < 4; ++jj) {
                float z0 = acc2[p][2 * kt3][jj];
                float z1 = acc2[p][2 * kt3 + 1][jj];
                bf[jj]     = (_Float16)(z0 * fast_sigmoid(z0));
                bf[jj + 4] = (_Float16)(z1 * fast_sigmoid(z1));
            }
            b3f[p][kt3] = bf;
        }
    }

    // --- layer 3 heads + fp32 CBF-QP epilogue straight from registers ---
    #pragma unroll
    for (int p = 0; p < 2; ++p) {
        floatx4 d = {0.0f, 0.0f, 0.0f, 0.0f};
        d = __builtin_amdgcn_mfma_f32_16x16x32_f16(w3f0, b3f[p][0], d, 0, 0, 0);
        d = __builtin_amdgcn_mfma_f32_16x16x32_f16(w3f1, b3f[p][1], d, 0, 0, 0);
        // D[head=q*4+r][row=m]: q==0 lanes hold u0(r0), u1(r1), z32(r2) for
        // row m — no LDS round-trip needed.
        if (q == 0) {
            const float u0  = d[0] + bu0;
            const float u1  = d[1] + bu1;
            const float z32 = d[2] + bz3;
            const float alpha = 4.0f * fast_sigmoid(z32);

            const float2 rxy = *(const float2*)(orow[p] + 6);
            const float2 vxy = *(const float2*)(orow[p] + 8);
            const float rx = rxy.x, ry = rxy.y, vx = vxy.x, vy = vxy.y;

            const float barrier = rx * rx + ry * ry - 0.64f;   // R_SAFE^2
            const float lf = -2.0f * (rx * vx + ry * vy);
            const float gx = -2.0f * rx, gy = -2.0f * ry;
            const float h  = lf + alpha * barrier;
            const float gg = gx * gx + gy * gy;
            const float viol = gx * u0 + gy * u1 - h;
            float lam = 0.0f;
            if (gg > 0.0f) lam = fmaxf(viol, 0.0f) / fmaxf(gg, 1e-12f);

            float2 r;
            r.x = fmaf(-lam, gx, u0);
            r.y = fmaf(-lam, gy, u1);
            *(float2*)(out + (size_t)lrow0[p] * 2) = r;   // 16 rows, coalesced
        }
    }
}

extern "C" void kernel_launch(void* const* d_in, const int* in_sizes, int n_in,
                              void* d_out, int out_size, void* d_ws, size_t ws_size,
                              hipStream_t stream) {
    const float* obs = (const float*)d_in[0];
    const float* W1  = (const float*)d_in[1];
    const float* b1  = (const float*)d_in[2];
    const float* W21 = (const float*)d_in[3];
    const float* b21 = (const float*)d_in[4];
    const float* W22 = (const float*)d_in[5];
    const float* b22 = (const float*)d_in[6];
    const float* W31 = (const float*)d_in[7];
    const float* b31 = (const float*)d_in[8];
    const float* W32 = (const float*)d_in[9];
    const float* b32 = (const float*)d_in[10];

    unsigned char* ws = (unsigned char*)d_ws;

    prep_kernel<<<7, 256, 0, stream>>>(W1, b1, W21, b21, W22, b22,
                                       W31, b31, W32, b32, ws);

    const int B = in_sizes[0] / 10;                  // obs is [B,10]
    const int tiles = (B + 15) / 16;                 // 32768
    const int pairs = (tiles + 1) / 2;               // 16384
    const int grid  = (pairs + NW - 1) / NW;         // 4096

    barriernet_kernel<<<grid, TPB, 0, stream>>>(obs, ws, b31, b32,
                                                (float*)d_out, B);
}

// Round 11
// 120.437 us; speedup vs baseline: 1.0442x; 1.0297x over previous
//
#include <hip/hip_runtime.h>

// BarrierNet fused MLP + CBF-QP filter — output-transposed f16 MFMA, zero-LDS
// hot path, 4-way chain ILP.
//
// Structure (R10, kept): every layer computed transposed D = W·Xᵀ via
// mfma(Wfrag, Xfrag); next layer's B-fragment built IN-LANE from this
// layer's C-layout accumulators via H-permuted prepacked weights
// (H(kt,q,j) = (2kt+(j>>2))*16 + q*4 + (j&3)); L1 bias rides the k=10 pad
// slot; L3 transposed output lands u0,u1,z32 in q==0 lanes -> register
// epilogue. No LDS, no barriers, no cross-lane ops in the hot path.
//
// R11 change: FOUR interleaved chains per wave. R10 (2 chains) measured
// VALUBusy 45%, occupancy 19% — each tile is one serial register chain and
// the MFMA->VALU (acc read) / VALU->MFMA hazards are exposed dead cycles.
// 4 chains give the scheduler 3 other chains to fill every hazard window.
// R8's NT=4 failure modes don't apply here: no LDS tile to corrupt, and the
// zero-LDS body is ~2.2 KB/chain (fits L1I easily).
// L1 is restructured to pack b2f per kt-pair immediately (transient accs die
// after 2 MFMAs) so per-chain live stays ~30 regs; peak ~= weights 104 +
// 4*30 + xf 16 ~= 220 < 256. __launch_bounds__(256,2) — R4/R5 measured
// (256,3+) => allocator spills to scratch (WRITE_SIZE is the tripwire).
//
// Layouts (HW-verified, learn_hip m89/m91/m120):
//   A-frag: lane holds A[m=lane&15][k=(lane>>4)*8 + j], j=0..7
//   B-frag: lane holds B[k=(lane>>4)*8+j][n=lane&15]
//   C/D   : lane holds D[row=(lane>>4)*4+reg][col=lane&15]

typedef _Float16 half8 __attribute__((ext_vector_type(8)));
typedef float floatx4 __attribute__((ext_vector_type(4)));

#define TPB 256
#define NW  4          // waves per block
#define NT  4          // chains (16-row tiles) per wave

// d_ws layout (bytes). Fragments: half8[fragID][lane]; fragID 0..7 = W1
// n-tiles (k=10 slot carries b1), 8..23 = W2 (nt2*4+kt, H-permuted k),
// 24..25 = W3 heads (H-permuted k). Then bias table for L2 C-init.
#define WS_FRAG 0        // 26*64 half8 = 26624 B
#define WS_B2Q  26624    // 16 float4  =   256 B   [nt2][q] -> {bias r=0..3}

__device__ __forceinline__ float fast_sigmoid(float z) {
    return __builtin_amdgcn_rcpf(1.0f + __expf(-z));
}

// ---------------- prep: fp32 weights -> f16 fragments in ws ----------------
__global__ __launch_bounds__(256) void prep_kernel(
    const float* __restrict__ W1,  const float* __restrict__ b1,
    const float* __restrict__ W21, const float* __restrict__ b21,
    const float* __restrict__ W22, const float* __restrict__ b22,
    const float* __restrict__ W31, const float* __restrict__ b31,
    const float* __restrict__ W32, const float* __restrict__ b32,
    unsigned char* __restrict__ ws)
{
    const int tid  = blockIdx.x * 256 + threadIdx.x;
    const int lane = tid & 63;
    const int m    = lane & 15;
    const int q    = lane >> 4;

    if (tid < 26 * 64) {
        const int f = tid >> 6;
        float v[8];
        if (f < 8) {
            // Ŵ1 A-frag, n-tile f: A[m][k=q*8+j]; k<10 -> W1, k==10 -> b1.
            const float* wr = W1 + (f * 16 + m) * 10;
            #pragma unroll
            for (int j = 0; j < 8; ++j) {
                const int k = q * 8 + j;
                v[j] = (k < 10) ? wr[k] : (k == 10 ? b1[f * 16 + m] : 0.0f);
            }
        } else if (f < 24) {
            // Ŵ2 A-frag (nt2,kt), H-permuted k-order to match in-lane pack.
            const int f2 = f - 8, nt2 = f2 >> 2, kt = f2 & 3;
            const int n2 = nt2 * 16 + m;
            const float* wr = (n2 < 32) ? (W21 + n2 * 128)
                                        : (W22 + (n2 - 32) * 128);
            #pragma unroll
            for (int j = 0; j < 8; ++j) {
                const int H = (2 * kt + (j >> 2)) * 16 + q * 4 + (j & 3);
                v[j] = wr[H];
            }
        } else {
            // Ŵ3 A-frag kt3: rows = heads (u0,u1 from W31; z32 from W32),
            // H3-permuted k-order.
            const int kt3 = f - 24;
            #pragma unroll
            for (int j = 0; j < 8; ++j) {
                const int H3 = (2 * kt3 + (j >> 2)) * 16 + q * 4 + (j & 3);
                float x = 0.0f;
                if (m == 0)      x = (H3 < 32)  ? W31[H3]       : 0.0f;
                else if (m == 1) x = (H3 < 32)  ? W31[32 + H3]  : 0.0f;
                else if (m == 2) x = (H3 >= 32) ? W32[H3 - 32]  : 0.0f;
                v[j] = x;
            }
        }
        half8 h;
        #pragma unroll
        for (int j = 0; j < 8; ++j) h[j] = (_Float16)v[j];
        ((half8*)(ws + WS_FRAG))[tid] = h;
    }
    if (tid < 16) {
        // L2 bias C-init table: [nt2][q] -> bias for out = nt2*16+q*4+r.
        const int nt2 = tid >> 2, qq = tid & 3;
        float4 v;
        float* vp = (float*)&v;
        #pragma unroll
        for (int r = 0; r < 4; ++r) {
            const int n2 = nt2 * 16 + qq * 4 + r;
            vp[r] = (n2 < 32) ? b21[n2] : b22[n2 - 32];
        }
        ((float4*)(ws + WS_B2Q))[tid] = v;
    }
}

// ------------------------------- main -------------------------------------
__global__ __launch_bounds__(TPB, 2) void barriernet_kernel(
    const float* __restrict__ obs,
    const unsigned char* __restrict__ ws,
    const float* __restrict__ b31, const float* __restrict__ b32,
    float* __restrict__ out, int B)
{
    const int tid  = threadIdx.x;
    const int wave = tid >> 6;
    const int lane = tid & 63;
    const int m    = lane & 15;
    const int q    = lane >> 4;

    // ---- weight fragments: 26 coalesced b128 loads + 4 float4 bias loads ----
    const half8* wf = (const half8*)(ws + WS_FRAG);
    half8 w1f[8], w2f[16], w3f0, w3f1;
    #pragma unroll
    for (int nt = 0; nt < 8; ++nt)  w1f[nt] = wf[nt * 64 + lane];
    #pragma unroll
    for (int f2 = 0; f2 < 16; ++f2) w2f[f2] = wf[(8 + f2) * 64 + lane];
    w3f0 = wf[24 * 64 + lane];
    w3f1 = wf[25 * 64 + lane];

    const float4* bt = (const float4*)(ws + WS_B2Q);
    float4 b2q[4];
    #pragma unroll
    for (int nt2 = 0; nt2 < 4; ++nt2) b2q[nt2] = bt[nt2 * 4 + q];

    const float bu0 = b31[0], bu1 = b31[1], bz3 = b32[0];  // uniform scalars

    const int tiles = (B + 15) >> 4;
    const int tbase = (blockIdx.x * NW + wave) * NT;

    // --- obs B-fragments for all chains (20 independent loads in flight) ---
    // B-frag: lane (q,m) holds obs[row=m][k=q*8+j]; k=10 slot := 1.0 (bias).
    const float* orow[NT];
    half8 xf[NT];
    int lrow0[NT];
    #pragma unroll
    for (int p = 0; p < NT; ++p) {
        int tile = tbase + p;
        if (tile >= tiles) tile = tiles - 1;            // dup work, benign
        int lr = (tile << 4) + m;
        if (lr >= B) lr = B - 1;
        lrow0[p] = lr;
        orow[p] = obs + (size_t)lr * 10;

        float g0=0,g1=0,g2=0,g3=0,g4=0,g5=0,g6=0,g7=0;
        if (q == 0) {
            float2 p0 = *(const float2*)(orow[p] + 0);
            float2 p1 = *(const float2*)(orow[p] + 2);
            float2 p2 = *(const float2*)(orow[p] + 4);
            float2 p3 = *(const float2*)(orow[p] + 6);
            g0=p0.x; g1=p0.y; g2=p1.x; g3=p1.y;
            g4=p2.x; g5=p2.y; g6=p3.x; g7=p3.y;
        } else if (q == 1) {
            float2 pp = *(const float2*)(orow[p] + 8);
            g0=pp.x; g1=pp.y;
            g2=1.0f;                                   // k=10: bias lane
        }
        xf[p][0]=(_Float16)g0; xf[p][1]=(_Float16)g1;
        xf[p][2]=(_Float16)g2; xf[p][3]=(_Float16)g3;
        xf[p][4]=(_Float16)g4; xf[p][5]=(_Float16)g5;
        xf[p][6]=(_Float16)g6; xf[p][7]=(_Float16)g7;
    }

    // --- layer 1 fused with silu+pack, per kt-pair: the 2 transient accs of
    // chain p die immediately into b2f[p][kt]; chains p interleave so the
    // MFMA->VALU hazard of one chain is filled by the next chain's MFMAs ---
    half8 b2f[NT][4];
    #pragma unroll
    for (int kt = 0; kt < 4; ++kt) {
        #pragma unroll
        for (int p = 0; p < NT; ++p) {
            const floatx4 zz = {0.0f, 0.0f, 0.0f, 0.0f};
            floatx4 a0 = __builtin_amdgcn_mfma_f32_16x16x32_f16(
                             w1f[2 * kt],     xf[p], zz, 0, 0, 0);
            floatx4 a1 = __builtin_amdgcn_mfma_f32_16x16x32_f16(
                             w1f[2 * kt + 1], xf[p], zz, 0, 0, 0);
            half8 bf;
            #pragma unroll
            for (int jj = 0; jj < 4; ++jj) {
                float z0 = a0[jj], z1 = a1[jj];
                bf[jj]     = (_Float16)(z0 * fast_sigmoid(z0));
                bf[jj + 4] = (_Float16)(z1 * fast_sigmoid(z1));
            }
            b2f[p][kt] = bf;
        }
    }

    // --- layer 2: 4 n-tiles x 4 k-steps per chain, bias C-init ---
    floatx4 acc2[NT][4];
    #pragma unroll
    for (int nt2 = 0; nt2 < 4; ++nt2) {
        #pragma unroll
        for (int p = 0; p < NT; ++p) {
            floatx4 z = {b2q[nt2].x, b2q[nt2].y, b2q[nt2].z, b2q[nt2].w};
            #pragma unroll
            for (int kt = 0; kt < 4; ++kt)
                z = __builtin_amdgcn_mfma_f32_16x16x32_f16(
                        w2f[nt2 * 4 + kt], b2f[p][kt], z, 0, 0, 0);
            acc2[p][nt2] = z;
        }
    }

    // --- silu + in-lane pack to L3 B-fragments ---
    half8 b3f[NT][2];
    #pragma unroll
    for (int kt3 = 0; kt3 < 2; ++kt3) {
        #pragma unroll
        for (int p = 0; p < NT; ++p) {
            half8 bf;
            #pragma unroll
            for (int jj = 0; jj < 4; ++jj) {
                float z0 = acc2[p][2 * kt3][jj];
                float z1 = acc2[p][2 * kt3 + 1][jj];
                bf[jj]     = (_Float16)(z0 * fast_sigmoid(z0));
                bf[jj + 4] = (_Float16)(z1 * fast_sigmoid(z1));
            }
            b3f[p][kt3] = bf;
        }
    }

    // --- layer 3 heads + fp32 CBF-QP epilogue straight from registers ---
    #pragma unroll
    for (int p = 0; p < NT; ++p) {
        floatx4 d = {0.0f, 0.0f, 0.0f, 0.0f};
        d = __builtin_amdgcn_mfma_f32_16x16x32_f16(w3f0, b3f[p][0], d, 0, 0, 0);
        d = __builtin_amdgcn_mfma_f32_16x16x32_f16(w3f1, b3f[p][1], d, 0, 0, 0);
        // D[head=q*4+r][row=m]: q==0 lanes hold u0(r0), u1(r1), z32(r2).
        if (q == 0) {
            const float u0  = d[0] + bu0;
            const float u1  = d[1] + bu1;
            const float z32 = d[2] + bz3;
            const float alpha = 4.0f * fast_sigmoid(z32);

            const float2 rxy = *(const float2*)(orow[p] + 6);
            const float2 vxy = *(const float2*)(orow[p] + 8);
            const float rx = rxy.x, ry = rxy.y, vx = vxy.x, vy = vxy.y;

            const float barrier = rx * rx + ry * ry - 0.64f;   // R_SAFE^2
            const float lf = -2.0f * (rx * vx + ry * vy);
            const float gx = -2.0f * rx, gy = -2.0f * ry;
            const float h  = lf + alpha * barrier;
            const float gg = gx * gx + gy * gy;
            const float viol = gx * u0 + gy * u1 - h;
            float lam = 0.0f;
            if (gg > 0.0f) lam = fmaxf(viol, 0.0f) / fmaxf(gg, 1e-12f);

            float2 r;
            r.x = fmaf(-lam, gx, u0);
            r.y = fmaf(-lam, gy, u1);
            *(float2*)(out + (size_t)lrow0[p] * 2) = r;   // 16 rows, coalesced
        }
    }
}

extern "C" void kernel_launch(void* const* d_in, const int* in_sizes, int n_in,
                              void* d_out, int out_size, void* d_ws, size_t ws_size,
                              hipStream_t stream) {
    const float* obs = (const float*)d_in[0];
    const float* W1  = (const float*)d_in[1];
    const float* b1  = (const float*)d_in[2];
    const float* W21 = (const float*)d_in[3];
    const float* b21 = (const float*)d_in[4];
    const float* W22 = (const float*)d_in[5];
    const float* b22 = (const float*)d_in[6];
    const float* W31 = (const float*)d_in[7];
    const float* b31 = (const float*)d_in[8];
    const float* W32 = (const float*)d_in[9];
    const float* b32 = (const float*)d_in[10];

    unsigned char* ws = (unsigned char*)d_ws;

    prep_kernel<<<7, 256, 0, stream>>>(W1, b1, W21, b21, W22, b22,
                                       W31, b31, W32, b32, ws);

    const int B = in_sizes[0] / 10;                   // obs is [B,10]
    const int tiles = (B + 15) / 16;                  // 32768
    const int wavesN = (tiles + NT - 1) / NT;         // 8192
    const int grid  = (wavesN + NW - 1) / NW;         // 2048

    barriernet_kernel<<<grid, TPB, 0, stream>>>(obs, ws, b31, b32,
                                                (float*)d_out, B);
}

// Round 12
// 118.381 us; speedup vs baseline: 1.0624x; 1.0174x over previous
//
#include <hip/hip_runtime.h>

// BarrierNet fused MLP + CBF-QP filter — output-transposed f16 MFMA,
// no-transpose dataflow, W2-in-LDS, pair-rcp silu, 3 waves/EU.
//
// Cross-round finding: VALU issue/tile ~= 1870 cyc in R6/R7/R9/R10/R11 —
// structure-independent. The budget is the 48 silu/lane/tile: v_exp+v_rcp
// at trans rate (~16 cyc/wave64) = ~1536 cyc/tile. The kernel is
// transcendental-issue bound; only VALU *density* differs between rounds
// (R7 56% -> 45us best; R11 46% -> 54us). Weights-in-regs (104) caps
// residency at 2 waves/SIMD — that's the density limiter.
//
// R12: (1) W2 fragments (64 regs worth) -> LDS, staged once per block;
// each frag ds_read_b128 once per tile-pair and feeds BOTH chains. Live
// regs ~140 -> __launch_bounds__(256,3) = 3 waves/SIMD. (2) pair-rcp silu:
// sigma0,sigma1 share one v_rcp (r=rcp(d0*d1); s_i=r*d_other) — 48->24
// rcp/tile. exp input clamped (<=30) so d stays finite (no inf*0 NaN).
//
// Dataflow (R10, kept): D = W·X^T via mfma(Wfrag, Xfrag); next layer's
// B-fragment built IN-LANE from C-layout accs via H-permuted prepacked
// weights (H(kt,q,j) = (2kt+(j>>2))*16 + q*4 + (j&3)); L1 bias in k=10 pad
// slot; L3 heads land u0,u1,z32 in q==0 lanes -> register epilogue.
//
// Layouts (HW-verified, learn_hip m89/m91/m120):
//   A-frag: lane holds A[m=lane&15][k=(lane>>4)*8 + j], j=0..7
//   B-frag: lane holds B[k=(lane>>4)*8+j][n=lane&15]
//   C/D   : lane holds D[row=(lane>>4)*4+reg][col=lane&15]

typedef _Float16 half8 __attribute__((ext_vector_type(8)));
typedef float floatx4 __attribute__((ext_vector_type(4)));

#define TPB 256
#define NW  4          // waves per block

// d_ws layout (bytes). Fragments: half8[fragID][lane]; fragID 0..7 = W1
// n-tiles (k=10 slot carries b1), 8..23 = W2 (nt2*4+kt, H-permuted k),
// 24..25 = W3 heads (H-permuted k). Then bias table for L2 C-init.
#define WS_FRAG 0        // 26*64 half8 = 26624 B
#define WS_W2   8192     // byte offset of W2 frags (fragID 8)
#define WS_B2Q  26624    // 16 float4  =   256 B   [nt2][q] -> {bias r=0..3}

__device__ __forceinline__ float fast_sigmoid(float z) {
    return __builtin_amdgcn_rcpf(1.0f + __expf(-z));
}

// Two silus for one v_rcp: r = 1/(d0*d1); sig0 = r*d1, sig1 = r*d0.
// exp arg clamped to <=30 so d0*d1 stays finite (silu(z<=-30) ~= 0 anyway).
__device__ __forceinline__ void silu_pair(float z0, float z1,
                                          _Float16* o0, _Float16* o1) {
    float e0 = __expf(fminf(-z0, 30.0f));
    float e1 = __expf(fminf(-z1, 30.0f));
    float d0 = 1.0f + e0, d1 = 1.0f + e1;
    float r  = __builtin_amdgcn_rcpf(d0 * d1);
    *o0 = (_Float16)(z0 * d1 * r);
    *o1 = (_Float16)(z1 * d0 * r);
}

// ---------------- prep: fp32 weights -> f16 fragments in ws ----------------
__global__ __launch_bounds__(256) void prep_kernel(
    const float* __restrict__ W1,  const float* __restrict__ b1,
    const float* __restrict__ W21, const float* __restrict__ b21,
    const float* __restrict__ W22, const float* __restrict__ b22,
    const float* __restrict__ W31, const float* __restrict__ b31,
    const float* __restrict__ W32, const float* __restrict__ b32,
    unsigned char* __restrict__ ws)
{
    const int tid  = blockIdx.x * 256 + threadIdx.x;
    const int lane = tid & 63;
    const int m    = lane & 15;
    const int q    = lane >> 4;

    if (tid < 26 * 64) {
        const int f = tid >> 6;
        float v[8];
        if (f < 8) {
            // Ŵ1 A-frag, n-tile f: A[m][k=q*8+j]; k<10 -> W1, k==10 -> b1.
            const float* wr = W1 + (f * 16 + m) * 10;
            #pragma unroll
            for (int j = 0; j < 8; ++j) {
                const int k = q * 8 + j;
                v[j] = (k < 10) ? wr[k] : (k == 10 ? b1[f * 16 + m] : 0.0f);
            }
        } else if (f < 24) {
            // Ŵ2 A-frag (nt2,kt), H-permuted k-order to match in-lane pack.
            const int f2 = f - 8, nt2 = f2 >> 2, kt = f2 & 3;
            const int n2 = nt2 * 16 + m;
            const float* wr = (n2 < 32) ? (W21 + n2 * 128)
                                        : (W22 + (n2 - 32) * 128);
            #pragma unroll
            for (int j = 0; j < 8; ++j) {
                const int H = (2 * kt + (j >> 2)) * 16 + q * 4 + (j & 3);
                v[j] = wr[H];
            }
        } else {
            // Ŵ3 A-frag kt3: rows = heads (u0,u1 from W31; z32 from W32),
            // H3-permuted k-order.
            const int kt3 = f - 24;
            #pragma unroll
            for (int j = 0; j < 8; ++j) {
                const int H3 = (2 * kt3 + (j >> 2)) * 16 + q * 4 + (j & 3);
                float x = 0.0f;
                if (m == 0)      x = (H3 < 32)  ? W31[H3]       : 0.0f;
                else if (m == 1) x = (H3 < 32)  ? W31[32 + H3]  : 0.0f;
                else if (m == 2) x = (H3 >= 32) ? W32[H3 - 32]  : 0.0f;
                v[j] = x;
            }
        }
        half8 h;
        #pragma unroll
        for (int j = 0; j < 8; ++j) h[j] = (_Float16)v[j];
        ((half8*)(ws + WS_FRAG))[tid] = h;
    }
    if (tid < 16) {
        // L2 bias C-init table: [nt2][q] -> bias for out = nt2*16+q*4+r.
        const int nt2 = tid >> 2, qq = tid & 3;
        float4 v;
        float* vp = (float*)&v;
        #pragma unroll
        for (int r = 0; r < 4; ++r) {
            const int n2 = nt2 * 16 + qq * 4 + r;
            vp[r] = (n2 < 32) ? b21[n2] : b22[n2 - 32];
        }
        ((float4*)(ws + WS_B2Q))[tid] = v;
    }
}

// ------------------------------- main -------------------------------------
__global__ __launch_bounds__(TPB, 3) void barriernet_kernel(
    const float* __restrict__ obs,
    const unsigned char* __restrict__ ws,
    const float* __restrict__ b31, const float* __restrict__ b32,
    float* __restrict__ out, int B)
{
    __shared__ __align__(16) unsigned char lds[16384];   // W2 fragments

    const int tid  = threadIdx.x;
    const int wave = tid >> 6;
    const int lane = tid & 63;
    const int m    = lane & 15;
    const int q    = lane >> 4;

    // ---- stage W2 fragments (16 KB) into LDS: 4 float4 per thread ----
    {
        const float4* src = (const float4*)(ws + WS_W2);
        float4* dst = (float4*)lds;
        #pragma unroll
        for (int i = 0; i < 4; ++i) dst[tid + 256 * i] = src[tid + 256 * i];
    }
    __syncthreads();   // once; hot path below is barrier-free

    // W1/W3 fragments + biases -> registers (~60 regs total).
    const half8* wf = (const half8*)(ws + WS_FRAG);
    half8 w1f[8], w3f0, w3f1;
    #pragma unroll
    for (int nt = 0; nt < 8; ++nt) w1f[nt] = wf[nt * 64 + lane];
    w3f0 = wf[24 * 64 + lane];
    w3f1 = wf[25 * 64 + lane];

    const float4* bt = (const float4*)(ws + WS_B2Q);
    float4 b2q[4];
    #pragma unroll
    for (int nt2 = 0; nt2 < 4; ++nt2) b2q[nt2] = bt[nt2 * 4 + q];

    const float bu0 = b31[0], bu1 = b31[1], bz3 = b32[0];

    // W2 fragment f2 in LDS: byte f2*1024 + lane*16 (base reg + imm).
    const half8* w2l = ((const half8*)lds) + lane;

    const int tiles = (B + 15) >> 4;
    const int tbase = (blockIdx.x * NW + wave) * 2;

    // --- obs B-fragments for both chains ---
    const float* orow[2];
    half8 xf[2];
    int lrow0[2];
    #pragma unroll
    for (int p = 0; p < 2; ++p) {
        int tile = tbase + p;
        if (tile >= tiles) tile = tiles - 1;            // dup work, benign
        int lr = (tile << 4) + m;
        if (lr >= B) lr = B - 1;
        lrow0[p] = lr;
        orow[p] = obs + (size_t)lr * 10;

        float g0=0,g1=0,g2=0,g3=0,g4=0,g5=0,g6=0,g7=0;
        if (q == 0) {
            float2 p0 = *(const float2*)(orow[p] + 0);
            float2 p1 = *(const float2*)(orow[p] + 2);
            float2 p2 = *(const float2*)(orow[p] + 4);
            float2 p3 = *(const float2*)(orow[p] + 6);
            g0=p0.x; g1=p0.y; g2=p1.x; g3=p1.y;
            g4=p2.x; g5=p2.y; g6=p3.x; g7=p3.y;
        } else if (q == 1) {
            float2 pp = *(const float2*)(orow[p] + 8);
            g0=pp.x; g1=pp.y;
            g2=1.0f;                                   // k=10: bias lane
        }
        xf[p][0]=(_Float16)g0; xf[p][1]=(_Float16)g1;
        xf[p][2]=(_Float16)g2; xf[p][3]=(_Float16)g3;
        xf[p][4]=(_Float16)g4; xf[p][5]=(_Float16)g5;
        xf[p][6]=(_Float16)g6; xf[p][7]=(_Float16)g7;
    }

    // --- layer 1 fused with pair-rcp silu pack; transient accs die fast ---
    half8 b2f[2][4];
    #pragma unroll
    for (int kt = 0; kt < 4; ++kt) {
        #pragma unroll
        for (int p = 0; p < 2; ++p) {
            const floatx4 zz = {0.0f, 0.0f, 0.0f, 0.0f};
            floatx4 a0 = __builtin_amdgcn_mfma_f32_16x16x32_f16(
                             w1f[2 * kt],     xf[p], zz, 0, 0, 0);
            floatx4 a1 = __builtin_amdgcn_mfma_f32_16x16x32_f16(
                             w1f[2 * kt + 1], xf[p], zz, 0, 0, 0);
            half8 bf;
            #pragma unroll
            for (int jj = 0; jj < 4; ++jj) {
                _Float16 o0, o1;
                silu_pair(a0[jj], a1[jj], &o0, &o1);
                bf[jj] = o0; bf[jj + 4] = o1;
            }
            b2f[p][kt] = bf;
        }
    }

    // --- layer 2: each W2 fragment read ONCE from LDS, feeds both chains ---
    floatx4 acc2[2][4];
    #pragma unroll
    for (int nt2 = 0; nt2 < 4; ++nt2) {
        floatx4 zi = {b2q[nt2].x, b2q[nt2].y, b2q[nt2].z, b2q[nt2].w};
        acc2[0][nt2] = zi;
        acc2[1][nt2] = zi;
        #pragma unroll
        for (int kt = 0; kt < 4; ++kt) {
            half8 wfr = w2l[(nt2 * 4 + kt) * 64];     // ds_read_b128, imm off
            acc2[0][nt2] = __builtin_amdgcn_mfma_f32_16x16x32_f16(
                               wfr, b2f[0][kt], acc2[0][nt2], 0, 0, 0);
            acc2[1][nt2] = __builtin_amdgcn_mfma_f32_16x16x32_f16(
                               wfr, b2f[1][kt], acc2[1][nt2], 0, 0, 0);
        }
    }

    // --- pair-rcp silu pack to L3 B-fragments ---
    half8 b3f[2][2];
    #pragma unroll
    for (int kt3 = 0; kt3 < 2; ++kt3) {
        #pragma unroll
        for (int p = 0; p < 2; ++p) {
            half8 bf;
            #pragma unroll
            for (int jj = 0; jj < 4; ++jj) {
                _Float16 o0, o1;
                silu_pair(acc2[p][2 * kt3][jj], acc2[p][2 * kt3 + 1][jj],
                          &o0, &o1);
                bf[jj] = o0; bf[jj + 4] = o1;
            }
            b3f[p][kt3] = bf;
        }
    }

    // --- layer 3 heads + fp32 CBF-QP epilogue straight from registers ---
    #pragma unroll
    for (int p = 0; p < 2; ++p) {
        floatx4 d = {0.0f, 0.0f, 0.0f, 0.0f};
        d = __builtin_amdgcn_mfma_f32_16x16x32_f16(w3f0, b3f[p][0], d, 0, 0, 0);
        d = __builtin_amdgcn_mfma_f32_16x16x32_f16(w3f1, b3f[p][1], d, 0, 0, 0);
        // D[head=q*4+r][row=m]: q==0 lanes hold u0(r0), u1(r1), z32(r2).
        if (q == 0) {
            const float u0  = d[0] + bu0;
            const float u1  = d[1] + bu1;
            const float z32 = d[2] + bz3;
            const float alpha = 4.0f * fast_sigmoid(z32);

            const float2 rxy = *(const float2*)(orow[p] + 6);
            const float2 vxy = *(const float2*)(orow[p] + 8);
            const float rx = rxy.x, ry = rxy.y, vx = vxy.x, vy = vxy.y;

            const float barrier = rx * rx + ry * ry - 0.64f;   // R_SAFE^2
            const float lf = -2.0f * (rx * vx + ry * vy);
            const float gx = -2.0f * rx, gy = -2.0f * ry;
            const float h  = lf + alpha * barrier;
            const float gg = gx * gx + gy * gy;
            const float viol = gx * u0 + gy * u1 - h;
            float lam = 0.0f;
            if (gg > 0.0f)
                lam = fmaxf(viol, 0.0f) *
                      __builtin_amdgcn_rcpf(fmaxf(gg, 1e-12f));

            float2 r;
            r.x = fmaf(-lam, gx, u0);
            r.y = fmaf(-lam, gy, u1);
            *(float2*)(out + (size_t)lrow0[p] * 2) = r;   // 16 rows, coalesced
        }
    }
}

extern "C" void kernel_launch(void* const* d_in, const int* in_sizes, int n_in,
                              void* d_out, int out_size, void* d_ws, size_t ws_size,
                              hipStream_t stream) {
    const float* obs = (const float*)d_in[0];
    const float* W1  = (const float*)d_in[1];
    const float* b1  = (const float*)d_in[2];
    const float* W21 = (const float*)d_in[3];
    const float* b21 = (const float*)d_in[4];
    const float* W22 = (const float*)d_in[5];
    const float* b22 = (const float*)d_in[6];
    const float* W31 = (const float*)d_in[7];
    const float* b31 = (const float*)d_in[8];
    const float* W32 = (const float*)d_in[9];
    const float* b32 = (const float*)d_in[10];

    unsigned char* ws = (unsigned char*)d_ws;

    prep_kernel<<<7, 256, 0, stream>>>(W1, b1, W21, b21, W22, b22,
                                       W31, b31, W32, b32, ws);

    const int B = in_sizes[0] / 10;                   // obs is [B,10]
    const int tiles = (B + 15) / 16;                  // 32768
    const int pairs = (tiles + 1) / 2;                // 16384
    const int grid  = (pairs + NW - 1) / NW;          // 4096

    barriernet_kernel<<<grid, TPB, 0, stream>>>(obs, ws, b31, b32,
                                                (float*)d_out, B);
}

// Round 13
// 116.566 us; speedup vs baseline: 1.0789x; 1.0156x over previous
//
#include <hip/hip_runtime.h>

// BarrierNet fused MLP + CBF-QP filter — output-transposed f16 MFMA,
// no-transpose dataflow, ALL weights in LDS, pair-rcp silu, 4 waves/EU.
//
// Cross-round findings:
//  * VALU issue/tile ~1870 cyc is structure-independent (R6-R11): the 48
//    silu/lane/tile (v_exp + v_rcp at trans rate) dominate. Only VALU
//    *density* (occupancy x ILP) moves wall time.
//  * R12 (W2->LDS, bound-3, pair-rcp) -> kernel <43us (best).
//  * Weights held in VGPRs cap residency; each eviction step has paid off.
//
// R13: evict W1 (32 regs), W3 (8), b2q (16) to LDS too. Whole 26.9 KB
// weight image staged once per block (one __syncthreads; hot path
// barrier-free). W1 fragments are ds_read_b128 ONCE per pair and feed both
// chains. Peak live drops to ~90 regs -> __launch_bounds__(256,4) =
// 4 waves/SIMD (vs 3). LDS 26.9 KB -> 4+ blocks/CU, not LDS-capped.
// WRITE_SIZE is the spill tripwire (R3/R5: over-tight bound -> scratch).
//
// Dataflow (R10, kept): D = W·X^T via mfma(Wfrag, Xfrag); next layer's
// B-fragment built IN-LANE from C-layout accs via H-permuted prepacked
// weights (H(kt,q,j) = (2kt+(j>>2))*16 + q*4 + (j&3)); L1 bias in k=10 pad
// slot; L3 heads land u0,u1,z32 in q==0 lanes -> register epilogue.
// silu via pair-rcp: one v_rcp per two sigmoids (exp arg clamped <=30 so
// inf*0 NaN can't form).
//
// Layouts (HW-verified, learn_hip m89/m91/m120):
//   A-frag: lane holds A[m=lane&15][k=(lane>>4)*8 + j], j=0..7
//   B-frag: lane holds B[k=(lane>>4)*8+j][n=lane&15]
//   C/D   : lane holds D[row=(lane>>4)*4+reg][col=lane&15]

typedef _Float16 half8 __attribute__((ext_vector_type(8)));
typedef float floatx4 __attribute__((ext_vector_type(4)));

#define TPB 256
#define NW  4          // waves per block

// d_ws layout (bytes). Fragments: half8[fragID][lane]; fragID 0..7 = W1
// n-tiles (k=10 slot carries b1), 8..23 = W2 (nt2*4+kt, H-permuted k),
// 24..25 = W3 heads (H-permuted k). Then bias table for L2 C-init.
#define WS_FRAG 0        // 26*64 half8 = 26624 B
#define WS_B2Q  26624    // 16 float4  =   256 B   [nt2][q] -> {bias r=0..3}
#define WS_END  26880    // bytes staged into LDS (= 1680 float4)

__device__ __forceinline__ float fast_sigmoid(float z) {
    return __builtin_amdgcn_rcpf(1.0f + __expf(-z));
}

// Two silus for one v_rcp: r = 1/(d0*d1); sig0 = r*d1, sig1 = r*d0.
// exp arg clamped to <=30 so d0*d1 stays finite (silu(z<=-30) ~= 0 anyway).
__device__ __forceinline__ void silu_pair(float z0, float z1,
                                          _Float16* o0, _Float16* o1) {
    float e0 = __expf(fminf(-z0, 30.0f));
    float e1 = __expf(fminf(-z1, 30.0f));
    float d0 = 1.0f + e0, d1 = 1.0f + e1;
    float r  = __builtin_amdgcn_rcpf(d0 * d1);
    *o0 = (_Float16)(z0 * d1 * r);
    *o1 = (_Float16)(z1 * d0 * r);
}

// ---------------- prep: fp32 weights -> f16 fragments in ws ----------------
__global__ __launch_bounds__(256) void prep_kernel(
    const float* __restrict__ W1,  const float* __restrict__ b1,
    const float* __restrict__ W21, const float* __restrict__ b21,
    const float* __restrict__ W22, const float* __restrict__ b22,
    const float* __restrict__ W31, const float* __restrict__ b31,
    const float* __restrict__ W32, const float* __restrict__ b32,
    unsigned char* __restrict__ ws)
{
    const int tid  = blockIdx.x * 256 + threadIdx.x;
    const int lane = tid & 63;
    const int m    = lane & 15;
    const int q    = lane >> 4;

    if (tid < 26 * 64) {
        const int f = tid >> 6;
        float v[8];
        if (f < 8) {
            // Ŵ1 A-frag, n-tile f: A[m][k=q*8+j]; k<10 -> W1, k==10 -> b1.
            const float* wr = W1 + (f * 16 + m) * 10;
            #pragma unroll
            for (int j = 0; j < 8; ++j) {
                const int k = q * 8 + j;
                v[j] = (k < 10) ? wr[k] : (k == 10 ? b1[f * 16 + m] : 0.0f);
            }
        } else if (f < 24) {
            // Ŵ2 A-frag (nt2,kt), H-permuted k-order to match in-lane pack.
            const int f2 = f - 8, nt2 = f2 >> 2, kt = f2 & 3;
            const int n2 = nt2 * 16 + m;
            const float* wr = (n2 < 32) ? (W21 + n2 * 128)
                                        : (W22 + (n2 - 32) * 128);
            #pragma unroll
            for (int j = 0; j < 8; ++j) {
                const int H = (2 * kt + (j >> 2)) * 16 + q * 4 + (j & 3);
                v[j] = wr[H];
            }
        } else {
            // Ŵ3 A-frag kt3: rows = heads (u0,u1 from W31; z32 from W32),
            // H3-permuted k-order.
            const int kt3 = f - 24;
            #pragma unroll
            for (int j = 0; j < 8; ++j) {
                const int H3 = (2 * kt3 + (j >> 2)) * 16 + q * 4 + (j & 3);
                float x = 0.0f;
                if (m == 0)      x = (H3 < 32)  ? W31[H3]       : 0.0f;
                else if (m == 1) x = (H3 < 32)  ? W31[32 + H3]  : 0.0f;
                else if (m == 2) x = (H3 >= 32) ? W32[H3 - 32]  : 0.0f;
                v[j] = x;
            }
        }
        half8 h;
        #pragma unroll
        for (int j = 0; j < 8; ++j) h[j] = (_Float16)v[j];
        ((half8*)(ws + WS_FRAG))[tid] = h;
    }
    if (tid < 16) {
        // L2 bias C-init table: [nt2][q] -> bias for out = nt2*16+q*4+r.
        const int nt2 = tid >> 2, qq = tid & 3;
        float4 v;
        float* vp = (float*)&v;
        #pragma unroll
        for (int r = 0; r < 4; ++r) {
            const int n2 = nt2 * 16 + qq * 4 + r;
            vp[r] = (n2 < 32) ? b21[n2] : b22[n2 - 32];
        }
        ((float4*)(ws + WS_B2Q))[tid] = v;
    }
}

// ------------------------------- main -------------------------------------
__global__ __launch_bounds__(TPB, 4) void barriernet_kernel(
    const float* __restrict__ obs,
    const unsigned char* __restrict__ ws,
    const float* __restrict__ b31, const float* __restrict__ b32,
    float* __restrict__ out, int B)
{
    __shared__ __align__(16) unsigned char lds[WS_END];   // all weights

    const int tid  = threadIdx.x;
    const int wave = tid >> 6;
    const int lane = tid & 63;
    const int m    = lane & 15;
    const int q    = lane >> 4;

    // ---- stage full weight image (26.9 KB) into LDS ----
    {
        const float4* src = (const float4*)ws;
        float4* dst = (float4*)lds;
        for (int i = tid; i < WS_END / 16; i += TPB) dst[i] = src[i];
    }
    __syncthreads();   // once; hot path below is barrier-free

    // Fragment f lives at lds + f*1024 + lane*16 (base reg + imm offset).
    const half8*  wl   = ((const half8*)lds) + lane;
    const float4* b2qt = (const float4*)(lds + WS_B2Q);

    const float bu0 = b31[0], bu1 = b31[1], bz3 = b32[0];  // uniform s_loads

    const int tiles = (B + 15) >> 4;
    const int tbase = (blockIdx.x * NW + wave) * 2;

    // --- obs B-fragments for both chains ---
    // B-frag: lane (q,m) holds obs[row=m][k=q*8+j]; k=10 slot := 1.0 (bias).
    const float* orow[2];
    half8 xf[2];
    int lrow0[2];
    #pragma unroll
    for (int p = 0; p < 2; ++p) {
        int tile = tbase + p;
        if (tile >= tiles) tile = tiles - 1;            // dup work, benign
        int lr = (tile << 4) + m;
        if (lr >= B) lr = B - 1;
        lrow0[p] = lr;
        orow[p] = obs + (size_t)lr * 10;

        float g0=0,g1=0,g2=0,g3=0,g4=0,g5=0,g6=0,g7=0;
        if (q == 0) {
            float2 p0 = *(const float2*)(orow[p] + 0);
            float2 p1 = *(const float2*)(orow[p] + 2);
            float2 p2 = *(const float2*)(orow[p] + 4);
            float2 p3 = *(const float2*)(orow[p] + 6);
            g0=p0.x; g1=p0.y; g2=p1.x; g3=p1.y;
            g4=p2.x; g5=p2.y; g6=p3.x; g7=p3.y;
        } else if (q == 1) {
            float2 pp = *(const float2*)(orow[p] + 8);
            g0=pp.x; g1=pp.y;
            g2=1.0f;                                   // k=10: bias lane
        }
        xf[p][0]=(_Float16)g0; xf[p][1]=(_Float16)g1;
        xf[p][2]=(_Float16)g2; xf[p][3]=(_Float16)g3;
        xf[p][4]=(_Float16)g4; xf[p][5]=(_Float16)g5;
        xf[p][6]=(_Float16)g6; xf[p][7]=(_Float16)g7;
    }

    // --- layer 1: each W1 fragment pair read ONCE from LDS, feeds both
    // chains; fused pair-rcp silu pack (transient accs die immediately) ---
    half8 b2f[2][4];
    #pragma unroll
    for (int kt = 0; kt < 4; ++kt) {
        half8 w1a = wl[(2 * kt) * 64];                // ds_read_b128, imm off
        half8 w1b = wl[(2 * kt + 1) * 64];
        #pragma unroll
        for (int p = 0; p < 2; ++p) {
            const floatx4 zz = {0.0f, 0.0f, 0.0f, 0.0f};
            floatx4 a0 = __builtin_amdgcn_mfma_f32_16x16x32_f16(
                             w1a, xf[p], zz, 0, 0, 0);
            floatx4 a1 = __builtin_amdgcn_mfma_f32_16x16x32_f16(
                             w1b, xf[p], zz, 0, 0, 0);
            half8 bf;
            #pragma unroll
            for (int jj = 0; jj < 4; ++jj) {
                _Float16 o0, o1;
                silu_pair(a0[jj], a1[jj], &o0, &o1);
                bf[jj] = o0; bf[jj + 4] = o1;
            }
            b2f[p][kt] = bf;
        }
    }

    // --- layer 2: each W2 fragment read ONCE from LDS, feeds both chains;
    // bias C-init read from LDS table ---
    floatx4 acc2[2][4];
    #pragma unroll
    for (int nt2 = 0; nt2 < 4; ++nt2) {
        float4 bi = b2qt[nt2 * 4 + q];
        floatx4 zi = {bi.x, bi.y, bi.z, bi.w};
        acc2[0][nt2] = zi;
        acc2[1][nt2] = zi;
        #pragma unroll
        for (int kt = 0; kt < 4; ++kt) {
            half8 wfr = wl[(8 + nt2 * 4 + kt) * 64];  // ds_read_b128, imm off
            acc2[0][nt2] = __builtin_amdgcn_mfma_f32_16x16x32_f16(
                               wfr, b2f[0][kt], acc2[0][nt2], 0, 0, 0);
            acc2[1][nt2] = __builtin_amdgcn_mfma_f32_16x16x32_f16(
                               wfr, b2f[1][kt], acc2[1][nt2], 0, 0, 0);
        }
    }

    // --- pair-rcp silu pack to L3 B-fragments ---
    half8 b3f[2][2];
    #pragma unroll
    for (int kt3 = 0; kt3 < 2; ++kt3) {
        #pragma unroll
        for (int p = 0; p < 2; ++p) {
            half8 bf;
            #pragma unroll
            for (int jj = 0; jj < 4; ++jj) {
                _Float16 o0, o1;
                silu_pair(acc2[p][2 * kt3][jj], acc2[p][2 * kt3 + 1][jj],
                          &o0, &o1);
                bf[jj] = o0; bf[jj + 4] = o1;
            }
            b3f[p][kt3] = bf;
        }
    }

    // --- layer 3 heads + fp32 CBF-QP epilogue straight from registers ---
    half8 w3a = wl[24 * 64];
    half8 w3b = wl[25 * 64];
    #pragma unroll
    for (int p = 0; p < 2; ++p) {
        floatx4 d = {0.0f, 0.0f, 0.0f, 0.0f};
        d = __builtin_amdgcn_mfma_f32_16x16x32_f16(w3a, b3f[p][0], d, 0, 0, 0);
        d = __builtin_amdgcn_mfma_f32_16x16x32_f16(w3b, b3f[p][1], d, 0, 0, 0);
        // D[head=q*4+r][row=m]: q==0 lanes hold u0(r0), u1(r1), z32(r2).
        if (q == 0) {
            const float u0  = d[0] + bu0;
            const float u1  = d[1] + bu1;
            const float z32 = d[2] + bz3;
            const float alpha = 4.0f * fast_sigmoid(z32);

            const float2 rxy = *(const float2*)(orow[p] + 6);
            const float2 vxy = *(const float2*)(orow[p] + 8);
            const float rx = rxy.x, ry = rxy.y, vx = vxy.x, vy = vxy.y;

            const float barrier = rx * rx + ry * ry - 0.64f;   // R_SAFE^2
            const float lf = -2.0f * (rx * vx + ry * vy);
            const float gx = -2.0f * rx, gy = -2.0f * ry;
            const float h  = lf + alpha * barrier;
            const float gg = gx * gx + gy * gy;
            const float viol = gx * u0 + gy * u1 - h;
            float lam = 0.0f;
            if (gg > 0.0f)
                lam = fmaxf(viol, 0.0f) *
                      __builtin_amdgcn_rcpf(fmaxf(gg, 1e-12f));

            float2 r;
            r.x = fmaf(-lam, gx, u0);
            r.y = fmaf(-lam, gy, u1);
            *(float2*)(out + (size_t)lrow0[p] * 2) = r;   // 16 rows, coalesced
        }
    }
}

extern "C" void kernel_launch(void* const* d_in, const int* in_sizes, int n_in,
                              void* d_out, int out_size, void* d_ws, size_t ws_size,
                              hipStream_t stream) {
    const float* obs = (const float*)d_in[0];
    const float* W1  = (const float*)d_in[1];
    const float* b1  = (const float*)d_in[2];
    const float* W21 = (const float*)d_in[3];
    const float* b21 = (const float*)d_in[4];
    const float* W22 = (const float*)d_in[5];
    const float* b22 = (const float*)d_in[6];
    const float* W31 = (const float*)d_in[7];
    const float* b31 = (const float*)d_in[8];
    const float* W32 = (const float*)d_in[9];
    const float* b32 = (const float*)d_in[10];

    unsigned char* ws = (unsigned char*)d_ws;

    prep_kernel<<<7, 256, 0, stream>>>(W1, b1, W21, b21, W22, b22,
                                       W31, b31, W32, b32, ws);

    const int B = in_sizes[0] / 10;                   // obs is [B,10]
    const int tiles = (B + 15) / 16;                  // 32768
    const int pairs = (tiles + 1) / 2;                // 16384
    const int grid  = (pairs + NW - 1) / NW;          // 4096

    barriernet_kernel<<<grid, TPB, 0, stream>>>(obs, ws, b31, b32,
                                                (float*)d_out, B);
}